// Round 2
// baseline (213.353 us; speedup 1.0000x reference)
//
#include <hip/hip_runtime.h>

// PairwiseAUCLoss: per class c (C=14), take the FIRST 32 positive-target
// logits and FIRST 64 negative-target logits (in row order), compute
// mean over valid pairs of softplus(-(pos - neg)), then mean over active
// classes. Targets in {-1,0,1}: -1 ignore, 0 neg, 1 pos.
//
// R2: batch-prefetch 384 rows (targets+logits) into registers as 12
// independent loads -> ONE memory round-trip instead of ~8 serialized
// (the data-dependent early-exit in R1 forced per-iteration load
// serialization). Binomial(384, 1/3) has mean 128, sigma 9.2 -> P(<64
// negatives in 384 rows) ~ 7 sigma ~ 1e-11; a serialized fallback loop
// preserves exact correctness for that case.
//
// Measured context: harness re-poison fills (448 MiB d_ws poison etc.)
// account for ~206 us of the timed window; kernel-only time is the
// remainder (~6 us in R1). This targets the kernel-only latency.

#define B_ROWS 2097152
#define C_CLS 14
#define MAX_POS 32
#define MAX_NEG 64
#define PF_ITERS 6   // 384 rows prefetched

__device__ __forceinline__ float stable_softplus(float x) {
    // log(1 + exp(x)) = max(x,0) + log1p(exp(-|x|))
    return fmaxf(x, 0.0f) + log1pf(expf(-fabsf(x)));
}

__global__ __launch_bounds__(896) void pairwise_auc_kernel(
        const float* __restrict__ logits,
        const int* __restrict__ targets,
        float* __restrict__ out) {
    __shared__ float posBuf[C_CLS][MAX_POS];
    __shared__ float negBuf[C_CLS][MAX_NEG];
    __shared__ float lossS[C_CLS];
    __shared__ int activeS[C_CLS];

    const int tid = threadIdx.x;
    const int wave = tid >> 6;      // 0..13 -> class index
    const int lane = tid & 63;
    const int c = wave;

    const unsigned long long lmask = (1ull << lane) - 1ull;  // lanes below me

    // ---- Batch prefetch: all 12 loads independent, issued before any use ----
    int t[PF_ITERS];
    float v[PF_ITERS];
    #pragma unroll
    for (int j = 0; j < PF_ITERS; ++j) {
        const int idx = (lane + 64 * j) * C_CLS + c;   // max ~5.4k, int-safe
        t[j] = targets[idx];
        v[j] = logits[idx];
    }

    int cntPos = 0;   // wave-uniform (derived from ballots)
    int cntNeg = 0;
    bool done = false;

    #pragma unroll
    for (int j = 0; j < PF_ITERS; ++j) {
        if (!done) {   // wave-uniform condition
            const bool isPos = (t[j] == 1);
            const bool isNeg = (t[j] == 0);
            const unsigned long long pm = __ballot(isPos);
            const unsigned long long nm = __ballot(isNeg);
            if (isPos) {
                const int r = cntPos + (int)__popcll(pm & lmask);
                if (r < MAX_POS) posBuf[c][r] = v[j];
            } else if (isNeg) {
                const int r = cntNeg + (int)__popcll(nm & lmask);
                if (r < MAX_NEG) negBuf[c][r] = v[j];
            }
            cntPos = min(cntPos + (int)__popcll(pm), MAX_POS);
            cntNeg = min(cntNeg + (int)__popcll(nm), MAX_NEG);
            done = (cntPos >= MAX_POS) & (cntNeg >= MAX_NEG);
        }
    }

    // ---- Fallback scan (P ~ 1e-11; preserves exactness) ----
    for (long long base = 64 * PF_ITERS; base < B_ROWS && !done; base += 64) {
        const long long row = base + (long long)lane;
        const int tt = targets[row * C_CLS + c];
        const bool isPos = (tt == 1);
        const bool isNeg = (tt == 0);
        const unsigned long long pm = __ballot(isPos);
        const unsigned long long nm = __ballot(isNeg);
        if (isPos | isNeg) {
            const float vv = logits[row * C_CLS + c];
            if (isPos) {
                const int r = cntPos + (int)__popcll(pm & lmask);
                if (r < MAX_POS) posBuf[c][r] = vv;
            } else {
                const int r = cntNeg + (int)__popcll(nm & lmask);
                if (r < MAX_NEG) negBuf[c][r] = vv;
            }
        }
        cntPos = min(cntPos + (int)__popcll(pm), MAX_POS);
        cntNeg = min(cntNeg + (int)__popcll(nm), MAX_NEG);
        done = (cntPos >= MAX_POS) & (cntNeg >= MAX_NEG);
    }

    // Cross-lane LDS visibility (also covers the final cross-wave combine).
    __syncthreads();

    // Pairwise sum: lane j owns negBuf[c][j], loop over valid positives.
    float s = 0.0f;
    if (lane < cntNeg) {
        const float nv = negBuf[c][lane];
        for (int i = 0; i < cntPos; ++i) {
            const float d = posBuf[c][i] - nv;   // margin = 0
            s += stable_softplus(-d);
        }
    }
    // wave64 reduction
    #pragma unroll
    for (int off = 32; off > 0; off >>= 1)
        s += __shfl_down(s, off, 64);

    if (lane == 0) {
        const bool active = (cntPos > 0) && (cntNeg > 0);
        const float pairs = (float)cntPos * (float)cntNeg;
        lossS[c] = active ? (s / fmaxf(pairs, 1.0f)) : 0.0f;
        activeS[c] = active ? 1 : 0;
    }
    __syncthreads();

    if (tid == 0) {
        float tot = 0.0f;
        int cnt = 0;
        #pragma unroll
        for (int i = 0; i < C_CLS; ++i) {
            tot += lossS[i];
            cnt += activeS[i];
        }
        out[0] = (cnt > 0) ? (tot / (float)cnt) : 0.0f;
    }
}

extern "C" void kernel_launch(void* const* d_in, const int* in_sizes, int n_in,
                              void* d_out, int out_size, void* d_ws, size_t ws_size,
                              hipStream_t stream) {
    const float* logits = (const float*)d_in[0];
    const int* targets = (const int*)d_in[1];
    float* out = (float*)d_out;
    (void)in_sizes; (void)n_in; (void)out_size; (void)d_ws; (void)ws_size;

    pairwise_auc_kernel<<<1, 896, 0, stream>>>(logits, targets, out);
}